// Round 1
// baseline (1473.470 us; speedup 1.0000x reference)
//
#include <hip/hip_runtime.h>
#include <hip/hip_bf16.h>

#define N_NODES 100000
#define N_EDGES 640000
#define NGRAPH 16

// ---------------- degree / norm ----------------
__global__ void deg_kernel(const int* __restrict__ src, const int* __restrict__ dst,
                           float* __restrict__ dout, float* __restrict__ din, int E) {
    int i = blockIdx.x * blockDim.x + threadIdx.x;
    if (i < E) {
        atomicAdd(&dout[src[i]], 1.0f);
        atomicAdd(&din[dst[i]], 1.0f);
    }
}

__global__ void rsqrt_kernel(float* __restrict__ a, float* __restrict__ b, int n) {
    int i = blockIdx.x * blockDim.x + threadIdx.x;
    if (i < n) {
        a[i] = rsqrtf(fmaxf(a[i], 1.0f));
        b[i] = rsqrtf(fmaxf(b[i], 1.0f));
    }
}

// ---------------- GEMM: out[r][c] = (sum_k A[r][k]*W[k][c]) * scale[r] ----------------
// 256 threads; M in {64,128}; rows/block = (256/M)*16
template<int K, int M>
__global__ __launch_bounds__(256) void gemm_scale(const float* __restrict__ A,
                                                  const float* __restrict__ W,
                                                  const float* __restrict__ scale,
                                                  float* __restrict__ out, int n) {
    constexpr int G = 256 / M;   // row groups
    constexpr int RT = 16;       // rows per thread
    constexpr int R = G * RT;    // rows per block
    __shared__ float a_tile[R][K];
    int row0 = blockIdx.x * R;
    for (int idx = threadIdx.x; idx < R * K; idx += 256) {
        int r = idx / K, k = idx % K;
        int gr = row0 + r;
        a_tile[r][k] = (gr < n) ? A[(size_t)gr * K + k] : 0.0f;
    }
    __syncthreads();
    int col = threadIdx.x % M;
    int rg  = threadIdx.x / M;
    float acc[RT];
#pragma unroll
    for (int i = 0; i < RT; i++) acc[i] = 0.0f;
#pragma unroll 4
    for (int k = 0; k < K; k++) {
        float w = W[k * M + col];
#pragma unroll
        for (int i = 0; i < RT; i++)
            acc[i] += a_tile[rg * RT + i][k] * w;
    }
#pragma unroll
    for (int i = 0; i < RT; i++) {
        int r = row0 + rg * RT + i;
        if (r < n) out[(size_t)r * M + col] = acc[i] * scale[r];
    }
}

// ---------------- edge scatter-add: m[dst[e]] += x[src[e]] ----------------
template<int LOGD>
__global__ void scatter_add(const float* __restrict__ x, const int* __restrict__ src,
                            const int* __restrict__ dst, float* __restrict__ m, int total) {
    int i = blockIdx.x * blockDim.x + threadIdx.x;
    if (i >= total) return;
    int e = i >> LOGD;
    int f = i & ((1 << LOGD) - 1);
    int s = src[e], d = dst[e];
    atomicAdd(&m[((size_t)d << LOGD) + f], x[((size_t)s << LOGD) + f]);
}

// ---------------- x = relu(m * c_dst[row] + b[col]) (in-place ok) ----------------
template<int LOGD>
__global__ void post_kernel(const float* __restrict__ m, const float* __restrict__ cdst,
                            const float* __restrict__ b, float* __restrict__ out, int total) {
    int i = blockIdx.x * blockDim.x + threadIdx.x;
    if (i >= total) return;
    int r = i >> LOGD, f = i & ((1 << LOGD) - 1);
    out[i] = fmaxf(fmaf(m[i], cdst[r], b[f]), 0.0f);
}

// ---------------- per-graph mean pooling (sum + count) ----------------
__global__ void pool_kernel(const float* __restrict__ x, const int* __restrict__ gid,
                            float* __restrict__ sums, float* __restrict__ cnts, int n) {
    __shared__ float ls[NGRAPH * 64];
    __shared__ float lc[NGRAPH];
    for (int i = threadIdx.x; i < NGRAPH * 64; i += blockDim.x) ls[i] = 0.0f;
    if (threadIdx.x < NGRAPH) lc[threadIdx.x] = 0.0f;
    __syncthreads();
    int total = n * 64;
    for (int i = blockIdx.x * blockDim.x + threadIdx.x; i < total;
         i += gridDim.x * blockDim.x) {
        int node = i >> 6, f = i & 63;
        int g = gid[node];
        atomicAdd(&ls[g * 64 + f], x[i]);
        if (f == 0) atomicAdd(&lc[g], 1.0f);
    }
    __syncthreads();
    for (int i = threadIdx.x; i < NGRAPH * 64; i += blockDim.x) atomicAdd(&sums[i], ls[i]);
    if (threadIdx.x < NGRAPH) atomicAdd(&cnts[threadIdx.x], lc[threadIdx.x]);
}

// ---------------- attention head: A = tanh(x @ aW1 + ab1) @ aW2 + ab2 ----------------
__global__ __launch_bounds__(256) void attn_kernel(const float* __restrict__ x,
                                                   const float* __restrict__ aW1,
                                                   const float* __restrict__ ab1,
                                                   const float* __restrict__ aW2,
                                                   const float* __restrict__ ab2,
                                                   float* __restrict__ A, int n) {
    __shared__ float w1[64 * 64];
    __shared__ float b1s[64];
    __shared__ float w2[64];
    for (int i = threadIdx.x; i < 64 * 64; i += 256) w1[i] = aW1[i];
    if (threadIdx.x < 64) { b1s[threadIdx.x] = ab1[threadIdx.x]; w2[threadIdx.x] = aW2[threadIdx.x]; }
    __syncthreads();
    int lane = threadIdx.x & 63;
    int wave = threadIdx.x >> 6;
    float bias2 = ab2[0];
    int node = blockIdx.x * 4 + wave;
    if (node >= n) return;
    float xv = x[(size_t)node * 64 + lane];
    float acc = b1s[lane];
#pragma unroll
    for (int k = 0; k < 64; k++) {
        float xk = __shfl(xv, k, 64);
        acc += xk * w1[k * 64 + lane];
    }
    float y = tanhf(acc);
    float p = y * w2[lane];
#pragma unroll
    for (int off = 32; off > 0; off >>= 1) p += __shfl_xor(p, off, 64);
    if (lane == 0) A[node] = p + bias2;
}

// ---------------- graph head: out = relu(hg @ cW1 + cb1) @ cW2 + cb2 ----------------
__global__ __launch_bounds__(1024) void head_kernel(const float* __restrict__ sums,
                                                    const float* __restrict__ cnts,
                                                    const float* __restrict__ cW1,
                                                    const float* __restrict__ cb1,
                                                    const float* __restrict__ cW2,
                                                    const float* __restrict__ cb2,
                                                    float* __restrict__ out) {
    __shared__ float hg[NGRAPH][64];
    __shared__ float z[NGRAPH][64];
    int tid = threadIdx.x;
    int g = tid >> 6, j = tid & 63;
    hg[g][j] = sums[tid] / fmaxf(cnts[g], 1.0f);
    __syncthreads();
    float acc = cb1[j];
#pragma unroll 4
    for (int k = 0; k < 64; k++) acc += hg[g][k] * cW1[k * 64 + j];
    z[g][j] = fmaxf(acc, 0.0f);
    __syncthreads();
    if (tid < NGRAPH * 2) {
        int gg = tid >> 1, c = tid & 1;
        float a2 = cb2[c];
#pragma unroll
        for (int jj = 0; jj < 64; jj++) a2 += z[gg][jj] * cW2[jj * 2 + c];
        out[gg * 2 + c] = a2;
    }
}

extern "C" void kernel_launch(void* const* d_in, const int* in_sizes, int n_in,
                              void* d_out, int out_size, void* d_ws, size_t ws_size,
                              hipStream_t stream) {
    const float* h   = (const float*)d_in[0];
    const int*   src = (const int*)d_in[1];
    const int*   dst = (const int*)d_in[2];
    const int*   gid = (const int*)d_in[3];
    const float* W1  = (const float*)d_in[4];
    const float* b1  = (const float*)d_in[5];
    const float* W2  = (const float*)d_in[6];
    const float* b2  = (const float*)d_in[7];
    const float* W3  = (const float*)d_in[8];
    const float* b3  = (const float*)d_in[9];
    const float* aW1 = (const float*)d_in[10];
    const float* ab1 = (const float*)d_in[11];
    const float* aW2 = (const float*)d_in[12];
    const float* ab2 = (const float*)d_in[13];
    const float* cW1 = (const float*)d_in[14];
    const float* cb1 = (const float*)d_in[15];
    const float* cW2 = (const float*)d_in[16];
    const float* cb2 = (const float*)d_in[17];

    float* out = (float*)d_out;   // 16*2 = 32 floats
    float* A   = out + 32;        // N floats

    const int N = N_NODES, E = N_EDGES;
    float* ws    = (float*)d_ws;
    float* c_src = ws;                     // N
    float* c_dst = ws + N;                 // N
    float* bufA  = ws + 2 * (size_t)N;     // N*128
    float* bufB  = bufA + (size_t)N * 128; // N*128
    float* sums  = bufB + (size_t)N * 128; // 16*64
    float* cnts  = sums + NGRAPH * 64;     // 16

    // degrees -> rsqrt norms (in place)
    hipMemsetAsync(c_src, 0, 2 * (size_t)N * sizeof(float), stream);
    deg_kernel<<<(E + 255) / 256, 256, 0, stream>>>(src, dst, c_src, c_dst, E);
    rsqrt_kernel<<<(N + 255) / 256, 256, 0, stream>>>(c_src, c_dst, N);

    // ---- layer 1: t1 = (h @ W1) * c_src -> bufA ; aggregate -> bufB ; relu+bias -> bufB
    gemm_scale<256, 128><<<(N + 31) / 32, 256, 0, stream>>>(h, W1, c_src, bufA, N);
    hipMemsetAsync(bufB, 0, (size_t)N * 128 * sizeof(float), stream);
    scatter_add<7><<<(E * 128 + 255) / 256, 256, 0, stream>>>(bufA, src, dst, bufB, E * 128);
    post_kernel<7><<<(N * 128 + 255) / 256, 256, 0, stream>>>(bufB, c_dst, b1, bufB, N * 128);

    // ---- layer 2
    gemm_scale<128, 128><<<(N + 31) / 32, 256, 0, stream>>>(bufB, W2, c_src, bufA, N);
    hipMemsetAsync(bufB, 0, (size_t)N * 128 * sizeof(float), stream);
    scatter_add<7><<<(E * 128 + 255) / 256, 256, 0, stream>>>(bufA, src, dst, bufB, E * 128);
    post_kernel<7><<<(N * 128 + 255) / 256, 256, 0, stream>>>(bufB, c_dst, b2, bufB, N * 128);

    // ---- layer 3: t3 -> bufA[0:N*64], m3 -> bufA[N*64:]
    float* t3 = bufA;
    float* m3 = bufA + (size_t)N * 64;
    gemm_scale<128, 64><<<(N + 63) / 64, 256, 0, stream>>>(bufB, W3, c_src, t3, N);
    hipMemsetAsync(m3, 0, (size_t)N * 64 * sizeof(float), stream);
    scatter_add<6><<<(E * 64 + 255) / 256, 256, 0, stream>>>(t3, src, dst, m3, E * 64);
    post_kernel<6><<<(N * 64 + 255) / 256, 256, 0, stream>>>(m3, c_dst, b3, m3, N * 64);
    float* x3 = m3;

    // ---- pooling
    hipMemsetAsync(sums, 0, (NGRAPH * 64 + NGRAPH) * sizeof(float), stream);
    pool_kernel<<<512, 256, 0, stream>>>(x3, gid, sums, cnts, N);

    // ---- attention scores A [N]
    attn_kernel<<<(N + 3) / 4, 256, 0, stream>>>(x3, aW1, ab1, aW2, ab2, A, N);

    // ---- graph head out [16,2]
    head_kernel<<<1, 1024, 0, stream>>>(sums, cnts, cW1, cb1, cW2, cb2, out);
}

// Round 2
// 1181.023 us; speedup vs baseline: 1.2476x; 1.2476x over previous
//
#include <hip/hip_runtime.h>
#include <hip/hip_bf16.h>

#define N_NODES 100000
#define N_EDGES 640000
#define NGRAPH 16

// ---------------- int degree histogram (both directions) ----------------
__global__ void hist_kernel(const int* __restrict__ src, const int* __restrict__ dst,
                            int* __restrict__ dout, int* __restrict__ din, int E) {
    int i = blockIdx.x * blockDim.x + threadIdx.x;
    if (i < E) {
        atomicAdd(&dout[src[i]], 1);
        atomicAdd(&din[dst[i]], 1);
    }
}

// c_src[i] = rsqrt(max(deg_out,1))
__global__ void csrc_kernel(const int* __restrict__ dout, float* __restrict__ c_src, int n) {
    int i = blockIdx.x * blockDim.x + threadIdx.x;
    if (i < n) c_src[i] = rsqrtf(fmaxf((float)dout[i], 1.0f));
}

// ---------------- one-block exclusive scan: deg (in deg_cur) -> row_ptr; deg_cur <- cursor copy ----------------
__global__ __launch_bounds__(1024) void scan_kernel(int* deg_cur, int* __restrict__ row_ptr, int n) {
    __shared__ int part[1024];
    int t = threadIdx.x;
    int per = (n + 1023) / 1024;
    int lo = t * per;
    int hi = min(lo + per, n);
    int s = 0;
    for (int i = lo; i < hi; i++) s += deg_cur[i];
    part[t] = s;
    __syncthreads();
    for (int off = 1; off < 1024; off <<= 1) {
        int v = (t >= off) ? part[t - off] : 0;
        __syncthreads();
        part[t] += v;
        __syncthreads();
    }
    int run = (t > 0) ? part[t - 1] : 0;
    for (int i = lo; i < hi; i++) {
        int d = deg_cur[i];
        row_ptr[i] = run;
        deg_cur[i] = run;   // becomes the fill cursor
        run += d;
    }
    if (t == 1023) row_ptr[n] = run;  // == E
}

// ---------------- CSR fill: bucket src ids by dst ----------------
__global__ void fill_kernel(const int* __restrict__ src, const int* __restrict__ dst,
                            int* __restrict__ cursor, int* __restrict__ csr_src, int E) {
    int i = blockIdx.x * blockDim.x + threadIdx.x;
    if (i < E) {
        int p = atomicAdd(&cursor[dst[i]], 1);
        csr_src[p] = src[i];
    }
}

// ---------------- GEMM: out[r][c] = (sum_k A[r][k]*W[k][c]) * scale[r] ----------------
template<int K, int M>
__global__ __launch_bounds__(256) void gemm_scale(const float* __restrict__ A,
                                                  const float* __restrict__ W,
                                                  const float* __restrict__ scale,
                                                  float* __restrict__ out, int n) {
    constexpr int G = 256 / M;   // row groups
    constexpr int RT = 16;       // rows per thread
    constexpr int R = G * RT;    // rows per block
    __shared__ float a_tile[R][K];
    int row0 = blockIdx.x * R;
    for (int idx = threadIdx.x; idx < R * K; idx += 256) {
        int r = idx / K, k = idx % K;
        int gr = row0 + r;
        a_tile[r][k] = (gr < n) ? A[(size_t)gr * K + k] : 0.0f;
    }
    __syncthreads();
    int col = threadIdx.x % M;
    int rg  = threadIdx.x / M;
    float acc[RT];
#pragma unroll
    for (int i = 0; i < RT; i++) acc[i] = 0.0f;
#pragma unroll 4
    for (int k = 0; k < K; k++) {
        float w = W[k * M + col];
#pragma unroll
        for (int i = 0; i < RT; i++)
            acc[i] += a_tile[rg * RT + i][k] * w;
    }
#pragma unroll
    for (int i = 0; i < RT; i++) {
        int r = row0 + rg * RT + i;
        if (r < n) out[(size_t)r * M + col] = acc[i] * scale[r];
    }
}

// ---------------- CSR gather-sum aggregation + fused (*c_dst + b) -> relu ----------------
// wave-per-node; D=128: each lane owns a float2; D=64: each lane owns one float
template<int D>
__global__ __launch_bounds__(256) void agg_relu(const float* __restrict__ x,
                                                const int* __restrict__ row_ptr,
                                                const int* __restrict__ csr_src,
                                                const float* __restrict__ bias,
                                                float* __restrict__ out, int n) {
    int lane = threadIdx.x & 63;
    int node = blockIdx.x * 4 + (threadIdx.x >> 6);
    if (node >= n) return;
    int p0 = row_ptr[node], p1 = row_ptr[node + 1];
    float cd = rsqrtf(fmaxf((float)(p1 - p0), 1.0f));
    if (D == 128) {
        float ax = 0.0f, ay = 0.0f;
        for (int p = p0; p < p1; ++p) {
            int s = csr_src[p];
            float2 v = ((const float2*)(x + ((size_t)s << 7)))[lane];
            ax += v.x; ay += v.y;
        }
        float2 b2 = ((const float2*)bias)[lane];
        float2 r;
        r.x = fmaxf(fmaf(ax, cd, b2.x), 0.0f);
        r.y = fmaxf(fmaf(ay, cd, b2.y), 0.0f);
        ((float2*)(out + ((size_t)node << 7)))[lane] = r;
    } else {
        float acc = 0.0f;
        for (int p = p0; p < p1; ++p) {
            int s = csr_src[p];
            acc += x[((size_t)s << 6) + lane];
        }
        out[((size_t)node << 6) + lane] = fmaxf(fmaf(acc, cd, bias[lane]), 0.0f);
    }
}

// ---------------- per-graph mean pooling (sum + count) ----------------
__global__ void pool_kernel(const float* __restrict__ x, const int* __restrict__ gid,
                            float* __restrict__ sums, float* __restrict__ cnts, int n) {
    __shared__ float ls[NGRAPH * 64];
    __shared__ float lc[NGRAPH];
    for (int i = threadIdx.x; i < NGRAPH * 64; i += blockDim.x) ls[i] = 0.0f;
    if (threadIdx.x < NGRAPH) lc[threadIdx.x] = 0.0f;
    __syncthreads();
    int total = n * 64;
    for (int i = blockIdx.x * blockDim.x + threadIdx.x; i < total;
         i += gridDim.x * blockDim.x) {
        int node = i >> 6, f = i & 63;
        int g = gid[node];
        atomicAdd(&ls[g * 64 + f], x[i]);
        if (f == 0) atomicAdd(&lc[g], 1.0f);
    }
    __syncthreads();
    for (int i = threadIdx.x; i < NGRAPH * 64; i += blockDim.x) atomicAdd(&sums[i], ls[i]);
    if (threadIdx.x < NGRAPH) atomicAdd(&cnts[threadIdx.x], lc[threadIdx.x]);
}

// ---------------- attention head: A = tanh(x @ aW1 + ab1) @ aW2 + ab2 ----------------
__global__ __launch_bounds__(256) void attn_kernel(const float* __restrict__ x,
                                                   const float* __restrict__ aW1,
                                                   const float* __restrict__ ab1,
                                                   const float* __restrict__ aW2,
                                                   const float* __restrict__ ab2,
                                                   float* __restrict__ A, int n) {
    __shared__ float w1[64 * 64];
    __shared__ float b1s[64];
    __shared__ float w2[64];
    for (int i = threadIdx.x; i < 64 * 64; i += 256) w1[i] = aW1[i];
    if (threadIdx.x < 64) { b1s[threadIdx.x] = ab1[threadIdx.x]; w2[threadIdx.x] = aW2[threadIdx.x]; }
    __syncthreads();
    int lane = threadIdx.x & 63;
    int wave = threadIdx.x >> 6;
    float bias2 = ab2[0];
    int node = blockIdx.x * 4 + wave;
    if (node >= n) return;
    float xv = x[(size_t)node * 64 + lane];
    float acc = b1s[lane];
#pragma unroll
    for (int k = 0; k < 64; k++) {
        float xk = __shfl(xv, k, 64);
        acc += xk * w1[k * 64 + lane];
    }
    float y = tanhf(acc);
    float p = y * w2[lane];
#pragma unroll
    for (int off = 32; off > 0; off >>= 1) p += __shfl_xor(p, off, 64);
    if (lane == 0) A[node] = p + bias2;
}

// ---------------- graph head: out = relu(hg @ cW1 + cb1) @ cW2 + cb2 ----------------
__global__ __launch_bounds__(1024) void head_kernel(const float* __restrict__ sums,
                                                    const float* __restrict__ cnts,
                                                    const float* __restrict__ cW1,
                                                    const float* __restrict__ cb1,
                                                    const float* __restrict__ cW2,
                                                    const float* __restrict__ cb2,
                                                    float* __restrict__ out) {
    __shared__ float hg[NGRAPH][64];
    __shared__ float z[NGRAPH][64];
    int tid = threadIdx.x;
    int g = tid >> 6, j = tid & 63;
    hg[g][j] = sums[tid] / fmaxf(cnts[g], 1.0f);
    __syncthreads();
    float acc = cb1[j];
#pragma unroll 4
    for (int k = 0; k < 64; k++) acc += hg[g][k] * cW1[k * 64 + j];
    z[g][j] = fmaxf(acc, 0.0f);
    __syncthreads();
    if (tid < NGRAPH * 2) {
        int gg = tid >> 1, c = tid & 1;
        float a2 = cb2[c];
#pragma unroll
        for (int jj = 0; jj < 64; jj++) a2 += z[gg][jj] * cW2[jj * 2 + c];
        out[gg * 2 + c] = a2;
    }
}

extern "C" void kernel_launch(void* const* d_in, const int* in_sizes, int n_in,
                              void* d_out, int out_size, void* d_ws, size_t ws_size,
                              hipStream_t stream) {
    const float* h   = (const float*)d_in[0];
    const int*   src = (const int*)d_in[1];
    const int*   dst = (const int*)d_in[2];
    const int*   gid = (const int*)d_in[3];
    const float* W1  = (const float*)d_in[4];
    const float* b1  = (const float*)d_in[5];
    const float* W2  = (const float*)d_in[6];
    const float* b2  = (const float*)d_in[7];
    const float* W3  = (const float*)d_in[8];
    const float* b3  = (const float*)d_in[9];
    const float* aW1 = (const float*)d_in[10];
    const float* ab1 = (const float*)d_in[11];
    const float* aW2 = (const float*)d_in[12];
    const float* ab2 = (const float*)d_in[13];
    const float* cW1 = (const float*)d_in[14];
    const float* cb1 = (const float*)d_in[15];
    const float* cW2 = (const float*)d_in[16];
    const float* cb2 = (const float*)d_in[17];

    float* out = (float*)d_out;   // 16*2 = 32 floats
    float* A   = out + 32;        // N floats

    const int N = N_NODES, E = N_EDGES;

    // ---- workspace layout (all 4-byte elems; bufA offset padded to 16-elem alignment)
    float* ws      = (float*)d_ws;
    float* c_src   = ws;                          // N floats
    int*   row_ptr = (int*)(ws + N);              // N+1 ints
    int*   cur     = row_ptr + (N + 1);           // N ints (din histogram, then fill cursor)
    int*   csr_src = cur + N;                     // E ints
    size_t off     = (size_t)N + (N + 1) + N + E;
    off = (off + 15) & ~(size_t)15;
    float* bufA    = ws + off;                    // N*128 floats
    float* bufB    = bufA + (size_t)N * 128;      // N*128 floats
    int*   dout    = (int*)bufB;                  // N ints (aliased: consumed before bufB written)
    float* sums    = bufB + (size_t)N * 128;      // 16*64
    float* cnts    = sums + NGRAPH * 64;          // 16

    // ---- CSR build (once, reused by all 3 layers)
    hipMemsetAsync(cur, 0, N * sizeof(int), stream);
    hipMemsetAsync(dout, 0, N * sizeof(int), stream);
    hist_kernel<<<(E + 255) / 256, 256, 0, stream>>>(src, dst, dout, cur, E);
    csrc_kernel<<<(N + 255) / 256, 256, 0, stream>>>(dout, c_src, N);
    scan_kernel<<<1, 1024, 0, stream>>>(cur, row_ptr, N);
    fill_kernel<<<(E + 255) / 256, 256, 0, stream>>>(src, dst, cur, csr_src, E);

    // ---- layer 1: bufA = (h @ W1) * c_src ; bufB = relu(agg * c_dst + b1)
    gemm_scale<256, 128><<<(N + 31) / 32, 256, 0, stream>>>(h, W1, c_src, bufA, N);
    agg_relu<128><<<(N + 3) / 4, 256, 0, stream>>>(bufA, row_ptr, csr_src, b1, bufB, N);

    // ---- layer 2
    gemm_scale<128, 128><<<(N + 31) / 32, 256, 0, stream>>>(bufB, W2, c_src, bufA, N);
    agg_relu<128><<<(N + 3) / 4, 256, 0, stream>>>(bufA, row_ptr, csr_src, b2, bufB, N);

    // ---- layer 3: t3 = bufA[0:N*64]; x3 = bufA[N*64:N*128]
    float* t3 = bufA;
    float* x3 = bufA + (size_t)N * 64;
    gemm_scale<128, 64><<<(N + 63) / 64, 256, 0, stream>>>(bufB, W3, c_src, t3, N);
    agg_relu<64><<<(N + 3) / 4, 256, 0, stream>>>(t3, row_ptr, csr_src, b3, x3, N);

    // ---- pooling
    hipMemsetAsync(sums, 0, (NGRAPH * 64 + NGRAPH) * sizeof(float), stream);
    pool_kernel<<<512, 256, 0, stream>>>(x3, gid, sums, cnts, N);

    // ---- attention scores A [N]
    attn_kernel<<<(N + 3) / 4, 256, 0, stream>>>(x3, aW1, ab1, aW2, ab2, A, N);

    // ---- graph head out [16,2]
    head_kernel<<<1, 1024, 0, stream>>>(sums, cnts, cW1, cb1, cW2, cb2, out);
}

// Round 3
// 964.190 us; speedup vs baseline: 1.5282x; 1.2249x over previous
//
#include <hip/hip_runtime.h>
#include <hip/hip_bf16.h>

#define N_NODES 100000
#define N_EDGES 640000
#define NGRAPH 16
#define STILE 4096  // scan tile: 256 threads * 16 elems

// ---------------- int degree histogram (both directions) ----------------
__global__ void hist_kernel(const int* __restrict__ src, const int* __restrict__ dst,
                            int* __restrict__ dout, int* __restrict__ din, int E) {
    int i = blockIdx.x * blockDim.x + threadIdx.x;
    if (i < E) {
        atomicAdd(&dout[src[i]], 1);
        atomicAdd(&din[dst[i]], 1);
    }
}

// c_src[i] = rsqrt(max(deg_out,1))
__global__ void csrc_kernel(const int* __restrict__ dout, float* __restrict__ c_src, int n) {
    int i = blockIdx.x * blockDim.x + threadIdx.x;
    if (i < n) c_src[i] = rsqrtf(fmaxf((float)dout[i], 1.0f));
}

// ---------------- multi-block exclusive scan, phase 1: tile-local scan ----------------
__global__ __launch_bounds__(256) void scan_blocks(const int* __restrict__ deg,
                                                   int* __restrict__ local,
                                                   int* __restrict__ blk_sums, int n) {
    __shared__ int wsum[4];
    int tid = threadIdx.x;
    int lane = tid & 63, wid = tid >> 6;
    int base = blockIdx.x * STILE + tid * 16;
    int v[16];
#pragma unroll
    for (int j = 0; j < 16; j++) {
        int idx = base + j;
        v[j] = (idx < n) ? deg[idx] : 0;
    }
    int tsum = 0;
#pragma unroll
    for (int j = 0; j < 16; j++) tsum += v[j];
    int inc = tsum;
    for (int off = 1; off < 64; off <<= 1) {
        int u = __shfl_up(inc, off, 64);
        if (lane >= off) inc += u;
    }
    if (lane == 63) wsum[wid] = inc;
    __syncthreads();
    int woff = 0;
#pragma unroll
    for (int w = 0; w < 4; w++) if (w < wid) woff += wsum[w];
    int run = woff + inc - tsum;   // exclusive offset for this thread
#pragma unroll
    for (int j = 0; j < 16; j++) {
        int idx = base + j;
        if (idx < n) local[idx] = run;
        run += v[j];
    }
    if (tid == 255) blk_sums[blockIdx.x] = woff + inc;  // tile total
}

// ---------------- phase 2: scan tile totals (nb <= 64) ----------------
__global__ void scan_tops(const int* __restrict__ blk_sums, int* __restrict__ blk_off,
                          int* __restrict__ row_ptr_n, int nb) {
    int lane = threadIdx.x;
    int v = (lane < nb) ? blk_sums[lane] : 0;
    int inc = v;
    for (int off = 1; off < 64; off <<= 1) {
        int u = __shfl_up(inc, off, 64);
        if (lane >= off) inc += u;
    }
    if (lane < nb) blk_off[lane] = inc - v;
    if (lane == 63) *row_ptr_n = inc;  // total == E
}

// ---------------- phase 3: add tile offsets; produce row_ptr + fill cursor ----------------
__global__ void scan_apply(const int* __restrict__ blk_off, int* __restrict__ row_ptr,
                           int* __restrict__ cur, int n) {
    int i = blockIdx.x * blockDim.x + threadIdx.x;
    if (i < n) {
        int v = row_ptr[i] + blk_off[i >> 12];
        row_ptr[i] = v;
        cur[i] = v;
    }
}

// ---------------- CSR fill: bucket src ids by dst ----------------
__global__ void fill_kernel(const int* __restrict__ src, const int* __restrict__ dst,
                            int* __restrict__ cursor, int* __restrict__ csr_src, int E) {
    int i = blockIdx.x * blockDim.x + threadIdx.x;
    if (i < E) {
        int p = atomicAdd(&cursor[dst[i]], 1);
        csr_src[p] = src[i];
    }
}

// ---------------- GEMM: out[r][c] = (sum_k A[r][k]*W[k][c]) * scale[r] ----------------
template<int K, int M>
__global__ __launch_bounds__(256) void gemm_scale(const float* __restrict__ A,
                                                  const float* __restrict__ W,
                                                  const float* __restrict__ scale,
                                                  float* __restrict__ out, int n) {
    constexpr int G = 256 / M;   // row groups
    constexpr int RT = 16;       // rows per thread
    constexpr int R = G * RT;    // rows per block
    __shared__ float a_tile[R][K];
    int row0 = blockIdx.x * R;
    for (int idx = threadIdx.x; idx < R * K; idx += 256) {
        int r = idx / K, k = idx % K;
        int gr = row0 + r;
        a_tile[r][k] = (gr < n) ? A[(size_t)gr * K + k] : 0.0f;
    }
    __syncthreads();
    int col = threadIdx.x % M;
    int rg  = threadIdx.x / M;
    float acc[RT];
#pragma unroll
    for (int i = 0; i < RT; i++) acc[i] = 0.0f;
#pragma unroll 4
    for (int k = 0; k < K; k++) {
        float w = W[k * M + col];
#pragma unroll
        for (int i = 0; i < RT; i++)
            acc[i] += a_tile[rg * RT + i][k] * w;
    }
#pragma unroll
    for (int i = 0; i < RT; i++) {
        int r = row0 + rg * RT + i;
        if (r < n) out[(size_t)r * M + col] = acc[i] * scale[r];
    }
}

// ---------------- CSR gather-sum aggregation + fused (*c_dst + b) -> relu ----------------
template<int D>
__global__ __launch_bounds__(256) void agg_relu(const float* __restrict__ x,
                                                const int* __restrict__ row_ptr,
                                                const int* __restrict__ csr_src,
                                                const float* __restrict__ bias,
                                                float* __restrict__ out, int n) {
    int lane = threadIdx.x & 63;
    int node = blockIdx.x * 4 + (threadIdx.x >> 6);
    if (node >= n) return;
    int p0 = row_ptr[node], p1 = row_ptr[node + 1];
    float cd = rsqrtf(fmaxf((float)(p1 - p0), 1.0f));
    if (D == 128) {
        float ax = 0.0f, ay = 0.0f;
        for (int p = p0; p < p1; ++p) {
            int s = csr_src[p];
            float2 v = ((const float2*)(x + ((size_t)s << 7)))[lane];
            ax += v.x; ay += v.y;
        }
        float2 b2 = ((const float2*)bias)[lane];
        float2 r;
        r.x = fmaxf(fmaf(ax, cd, b2.x), 0.0f);
        r.y = fmaxf(fmaf(ay, cd, b2.y), 0.0f);
        ((float2*)(out + ((size_t)node << 7)))[lane] = r;
    } else {
        float acc = 0.0f;
        for (int p = p0; p < p1; ++p) {
            int s = csr_src[p];
            acc += x[((size_t)s << 6) + lane];
        }
        out[((size_t)node << 6) + lane] = fmaxf(fmaf(acc, cd, bias[lane]), 0.0f);
    }
}

// ---------------- per-graph mean pooling (sum + count) ----------------
__global__ void pool_kernel(const float* __restrict__ x, const int* __restrict__ gid,
                            float* __restrict__ sums, float* __restrict__ cnts, int n) {
    __shared__ float ls[NGRAPH * 64];
    __shared__ float lc[NGRAPH];
    for (int i = threadIdx.x; i < NGRAPH * 64; i += blockDim.x) ls[i] = 0.0f;
    if (threadIdx.x < NGRAPH) lc[threadIdx.x] = 0.0f;
    __syncthreads();
    int total = n * 64;
    for (int i = blockIdx.x * blockDim.x + threadIdx.x; i < total;
         i += gridDim.x * blockDim.x) {
        int node = i >> 6, f = i & 63;
        int g = gid[node];
        atomicAdd(&ls[g * 64 + f], x[i]);
        if (f == 0) atomicAdd(&lc[g], 1.0f);
    }
    __syncthreads();
    for (int i = threadIdx.x; i < NGRAPH * 64; i += blockDim.x) atomicAdd(&sums[i], ls[i]);
    if (threadIdx.x < NGRAPH) atomicAdd(&cnts[threadIdx.x], lc[threadIdx.x]);
}

// ---------------- attention head: A = tanh(x @ aW1 + ab1) @ aW2 + ab2 ----------------
__global__ __launch_bounds__(256) void attn_kernel(const float* __restrict__ x,
                                                   const float* __restrict__ aW1,
                                                   const float* __restrict__ ab1,
                                                   const float* __restrict__ aW2,
                                                   const float* __restrict__ ab2,
                                                   float* __restrict__ A, int n) {
    __shared__ float w1[64 * 64];
    __shared__ float b1s[64];
    __shared__ float w2[64];
    for (int i = threadIdx.x; i < 64 * 64; i += 256) w1[i] = aW1[i];
    if (threadIdx.x < 64) { b1s[threadIdx.x] = ab1[threadIdx.x]; w2[threadIdx.x] = aW2[threadIdx.x]; }
    __syncthreads();
    int lane = threadIdx.x & 63;
    int wave = threadIdx.x >> 6;
    float bias2 = ab2[0];
    int node = blockIdx.x * 4 + wave;
    if (node >= n) return;
    float xv = x[(size_t)node * 64 + lane];
    float acc = b1s[lane];
#pragma unroll
    for (int k = 0; k < 64; k++) {
        float xk = __shfl(xv, k, 64);
        acc += xk * w1[k * 64 + lane];
    }
    float y = tanhf(acc);
    float p = y * w2[lane];
#pragma unroll
    for (int off = 32; off > 0; off >>= 1) p += __shfl_xor(p, off, 64);
    if (lane == 0) A[node] = p + bias2;
}

// ---------------- graph head: out = relu(hg @ cW1 + cb1) @ cW2 + cb2 ----------------
__global__ __launch_bounds__(1024) void head_kernel(const float* __restrict__ sums,
                                                    const float* __restrict__ cnts,
                                                    const float* __restrict__ cW1,
                                                    const float* __restrict__ cb1,
                                                    const float* __restrict__ cW2,
                                                    const float* __restrict__ cb2,
                                                    float* __restrict__ out) {
    __shared__ float hg[NGRAPH][64];
    __shared__ float z[NGRAPH][64];
    int tid = threadIdx.x;
    int g = tid >> 6, j = tid & 63;
    hg[g][j] = sums[tid] / fmaxf(cnts[g], 1.0f);
    __syncthreads();
    float acc = cb1[j];
#pragma unroll 4
    for (int k = 0; k < 64; k++) acc += hg[g][k] * cW1[k * 64 + j];
    z[g][j] = fmaxf(acc, 0.0f);
    __syncthreads();
    if (tid < NGRAPH * 2) {
        int gg = tid >> 1, c = tid & 1;
        float a2 = cb2[c];
#pragma unroll
        for (int jj = 0; jj < 64; jj++) a2 += z[gg][jj] * cW2[jj * 2 + c];
        out[gg * 2 + c] = a2;
    }
}

extern "C" void kernel_launch(void* const* d_in, const int* in_sizes, int n_in,
                              void* d_out, int out_size, void* d_ws, size_t ws_size,
                              hipStream_t stream) {
    const float* h   = (const float*)d_in[0];
    const int*   src = (const int*)d_in[1];
    const int*   dst = (const int*)d_in[2];
    const int*   gid = (const int*)d_in[3];
    const float* W1  = (const float*)d_in[4];
    const float* b1  = (const float*)d_in[5];
    const float* W2  = (const float*)d_in[6];
    const float* b2  = (const float*)d_in[7];
    const float* W3  = (const float*)d_in[8];
    const float* b3  = (const float*)d_in[9];
    const float* aW1 = (const float*)d_in[10];
    const float* ab1 = (const float*)d_in[11];
    const float* aW2 = (const float*)d_in[12];
    const float* ab2 = (const float*)d_in[13];
    const float* cW1 = (const float*)d_in[14];
    const float* cb1 = (const float*)d_in[15];
    const float* cW2 = (const float*)d_in[16];
    const float* cb2 = (const float*)d_in[17];

    float* out = (float*)d_out;   // 16*2 = 32 floats
    float* A   = out + 32;        // N floats

    const int N = N_NODES, E = N_EDGES;
    const int NB = (N + STILE - 1) / STILE;  // 25 scan tiles

    // ---- workspace layout
    float* ws       = (float*)d_ws;
    float* c_src    = ws;                          // N floats
    int*   row_ptr  = (int*)(ws + N);              // N+1 ints
    int*   cur      = row_ptr + (N + 1);           // N ints (din histogram -> fill cursor)
    int*   csr_src  = cur + N;                     // E ints
    int*   blk_sums = csr_src + E;                 // 64 ints
    int*   blk_off  = blk_sums + 64;               // 64 ints
    size_t off      = (size_t)N + (N + 1) + N + E + 128;
    off = (off + 15) & ~(size_t)15;
    float* bufA     = ws + off;                    // N*128 floats
    float* bufB     = bufA + (size_t)N * 128;      // N*128 floats
    int*   dout     = (int*)bufB;                  // N ints (aliased: consumed before bufB written)
    float* sums     = bufB + (size_t)N * 128;      // 16*64
    float* cnts     = sums + NGRAPH * 64;          // 16

    // ---- CSR build (once, reused by all 3 layers)
    hipMemsetAsync(cur, 0, N * sizeof(int), stream);
    hipMemsetAsync(dout, 0, N * sizeof(int), stream);
    hist_kernel<<<(E + 255) / 256, 256, 0, stream>>>(src, dst, dout, cur, E);
    csrc_kernel<<<(N + 255) / 256, 256, 0, stream>>>(dout, c_src, N);
    scan_blocks<<<NB, 256, 0, stream>>>(cur, row_ptr, blk_sums, N);
    scan_tops<<<1, 64, 0, stream>>>(blk_sums, blk_off, row_ptr + N, NB);
    scan_apply<<<(N + 255) / 256, 256, 0, stream>>>(blk_off, row_ptr, cur, N);
    fill_kernel<<<(E + 255) / 256, 256, 0, stream>>>(src, dst, cur, csr_src, E);

    // ---- layer 1: bufA = (h @ W1) * c_src ; bufB = relu(agg * c_dst + b1)
    gemm_scale<256, 128><<<(N + 31) / 32, 256, 0, stream>>>(h, W1, c_src, bufA, N);
    agg_relu<128><<<(N + 3) / 4, 256, 0, stream>>>(bufA, row_ptr, csr_src, b1, bufB, N);

    // ---- layer 2
    gemm_scale<128, 128><<<(N + 31) / 32, 256, 0, stream>>>(bufB, W2, c_src, bufA, N);
    agg_relu<128><<<(N + 3) / 4, 256, 0, stream>>>(bufA, row_ptr, csr_src, b2, bufB, N);

    // ---- layer 3: t3 = bufA[0:N*64]; x3 = bufA[N*64:N*128]
    float* t3 = bufA;
    float* x3 = bufA + (size_t)N * 64;
    gemm_scale<128, 64><<<(N + 63) / 64, 256, 0, stream>>>(bufB, W3, c_src, t3, N);
    agg_relu<64><<<(N + 3) / 4, 256, 0, stream>>>(t3, row_ptr, csr_src, b3, x3, N);

    // ---- pooling
    hipMemsetAsync(sums, 0, (NGRAPH * 64 + NGRAPH) * sizeof(float), stream);
    pool_kernel<<<512, 256, 0, stream>>>(x3, gid, sums, cnts, N);

    // ---- attention scores A [N]
    attn_kernel<<<(N + 3) / 4, 256, 0, stream>>>(x3, aW1, ab1, aW2, ab2, A, N);

    // ---- graph head out [16,2]
    head_kernel<<<1, 1024, 0, stream>>>(sums, cnts, cW1, cb1, cW2, cb2, out);
}

// Round 4
// 840.421 us; speedup vs baseline: 1.7533x; 1.1473x over previous
//
#include <hip/hip_runtime.h>
#include <hip/hip_bf16.h>

#define N_NODES 100000
#define N_EDGES 640000
#define NGRAPH 16
#define STILE 4096  // scan tile: 256 threads * 16 elems

// ---------------- int degree histogram (both directions) ----------------
__global__ void hist_kernel(const int* __restrict__ src, const int* __restrict__ dst,
                            int* __restrict__ dout, int* __restrict__ din, int E) {
    int i = blockIdx.x * blockDim.x + threadIdx.x;
    if (i < E) {
        atomicAdd(&dout[src[i]], 1);
        atomicAdd(&din[dst[i]], 1);
    }
}

// c_src[i] = rsqrt(max(deg_out,1))
__global__ void csrc_kernel(const int* __restrict__ dout, float* __restrict__ c_src, int n) {
    int i = blockIdx.x * blockDim.x + threadIdx.x;
    if (i < n) c_src[i] = rsqrtf(fmaxf((float)dout[i], 1.0f));
}

// ---------------- multi-block exclusive scan, phase 1: tile-local scan ----------------
__global__ __launch_bounds__(256) void scan_blocks(const int* __restrict__ deg,
                                                   int* __restrict__ local,
                                                   int* __restrict__ blk_sums, int n) {
    __shared__ int wsum[4];
    int tid = threadIdx.x;
    int lane = tid & 63, wid = tid >> 6;
    int base = blockIdx.x * STILE + tid * 16;
    int v[16];
#pragma unroll
    for (int j = 0; j < 16; j++) {
        int idx = base + j;
        v[j] = (idx < n) ? deg[idx] : 0;
    }
    int tsum = 0;
#pragma unroll
    for (int j = 0; j < 16; j++) tsum += v[j];
    int inc = tsum;
    for (int off = 1; off < 64; off <<= 1) {
        int u = __shfl_up(inc, off, 64);
        if (lane >= off) inc += u;
    }
    if (lane == 63) wsum[wid] = inc;
    __syncthreads();
    int woff = 0;
#pragma unroll
    for (int w = 0; w < 4; w++) if (w < wid) woff += wsum[w];
    int run = woff + inc - tsum;   // exclusive offset for this thread
#pragma unroll
    for (int j = 0; j < 16; j++) {
        int idx = base + j;
        if (idx < n) local[idx] = run;
        run += v[j];
    }
    if (tid == 255) blk_sums[blockIdx.x] = woff + inc;  // tile total
}

// ---------------- phase 2: scan tile totals (nb <= 64) ----------------
__global__ void scan_tops(const int* __restrict__ blk_sums, int* __restrict__ blk_off,
                          int* __restrict__ row_ptr_n, int nb) {
    int lane = threadIdx.x;
    int v = (lane < nb) ? blk_sums[lane] : 0;
    int inc = v;
    for (int off = 1; off < 64; off <<= 1) {
        int u = __shfl_up(inc, off, 64);
        if (lane >= off) inc += u;
    }
    if (lane < nb) blk_off[lane] = inc - v;
    if (lane == 63) *row_ptr_n = inc;  // total == E
}

// ---------------- phase 3: add tile offsets; produce row_ptr + fill cursor ----------------
__global__ void scan_apply(const int* __restrict__ blk_off, int* __restrict__ row_ptr,
                           int* __restrict__ cur, int n) {
    int i = blockIdx.x * blockDim.x + threadIdx.x;
    if (i < n) {
        int v = row_ptr[i] + blk_off[i >> 12];
        row_ptr[i] = v;
        cur[i] = v;
    }
}

// ---------------- CSR fill: bucket src ids by dst ----------------
__global__ void fill_kernel(const int* __restrict__ src, const int* __restrict__ dst,
                            int* __restrict__ cursor, int* __restrict__ csr_src, int E) {
    int i = blockIdx.x * blockDim.x + threadIdx.x;
    if (i < E) {
        int p = atomicAdd(&cursor[dst[i]], 1);
        csr_src[p] = src[i];
    }
}

// ---------------- register-tiled GEMM: out[r][c] = (sum_k A[r][k]*W[k][c]) * scale[r]
// 256 threads; thread tile RT rows x 4 cols; K chunked at 128; LDS [64][132]
template<int K, int M, int RT>
__global__ __launch_bounds__(256) void gemm_scale(const float* __restrict__ A,
                                                  const float* __restrict__ W,
                                                  const float* __restrict__ scale,
                                                  float* __restrict__ out, int n) {
    constexpr int KC = 128;           // k-chunk
    constexpr int CTH = M / 4;        // col-threads
    constexpr int R = (256 / CTH) * RT;  // rows per block (=64 for both configs)
    constexpr int LDW = KC + 4;       // LDS row stride (16B-aligned, conflict-free)
    __shared__ float a_tile[R][LDW];

    int tid = threadIdx.x;
    int col = (tid % CTH) * 4;
    int rg  = tid / CTH;              // row-group index
    int row0 = blockIdx.x * R;

    float4 acc[RT];
#pragma unroll
    for (int i = 0; i < RT; i++) acc[i] = make_float4(0.f, 0.f, 0.f, 0.f);

    for (int k0 = 0; k0 < K; k0 += KC) {
        // ---- stage A chunk: R rows x KC floats, coalesced float4 loads
        {
            constexpr int Q = KC / 4;             // float4 per row
            for (int idx = tid; idx < R * Q; idx += 256) {
                int r = idx / Q, q = idx % Q;
                int gr = row0 + r;
                float4 v = make_float4(0.f, 0.f, 0.f, 0.f);
                if (gr < n) v = *(const float4*)&A[(size_t)gr * K + k0 + q * 4];
                *(float4*)&a_tile[r][q * 4] = v;
            }
        }
        __syncthreads();
        // ---- compute
#pragma unroll 2
        for (int k = 0; k < KC; k += 4) {
            float4 wv0 = *(const float4*)&W[(size_t)(k0 + k + 0) * M + col];
            float4 wv1 = *(const float4*)&W[(size_t)(k0 + k + 1) * M + col];
            float4 wv2 = *(const float4*)&W[(size_t)(k0 + k + 2) * M + col];
            float4 wv3 = *(const float4*)&W[(size_t)(k0 + k + 3) * M + col];
#pragma unroll
            for (int i = 0; i < RT; i++) {
                float4 av = *(const float4*)&a_tile[rg * RT + i][k];
                acc[i].x = fmaf(av.x, wv0.x, acc[i].x);
                acc[i].y = fmaf(av.x, wv0.y, acc[i].y);
                acc[i].z = fmaf(av.x, wv0.z, acc[i].z);
                acc[i].w = fmaf(av.x, wv0.w, acc[i].w);
                acc[i].x = fmaf(av.y, wv1.x, acc[i].x);
                acc[i].y = fmaf(av.y, wv1.y, acc[i].y);
                acc[i].z = fmaf(av.y, wv1.z, acc[i].z);
                acc[i].w = fmaf(av.y, wv1.w, acc[i].w);
                acc[i].x = fmaf(av.z, wv2.x, acc[i].x);
                acc[i].y = fmaf(av.z, wv2.y, acc[i].y);
                acc[i].z = fmaf(av.z, wv2.z, acc[i].z);
                acc[i].w = fmaf(av.z, wv2.w, acc[i].w);
                acc[i].x = fmaf(av.w, wv3.x, acc[i].x);
                acc[i].y = fmaf(av.w, wv3.y, acc[i].y);
                acc[i].z = fmaf(av.w, wv3.z, acc[i].z);
                acc[i].w = fmaf(av.w, wv3.w, acc[i].w);
            }
        }
        __syncthreads();
    }
    // ---- epilogue: scale by c_src[row], store float4
#pragma unroll
    for (int i = 0; i < RT; i++) {
        int r = row0 + rg * RT + i;
        if (r < n) {
            float s = scale[r];
            float4 v = make_float4(acc[i].x * s, acc[i].y * s, acc[i].z * s, acc[i].w * s);
            *(float4*)&out[(size_t)r * M + col] = v;
        }
    }
}

// ---------------- CSR gather-sum aggregation + fused (*c_dst + b) -> relu ----------------
template<int D>
__global__ __launch_bounds__(256) void agg_relu(const float* __restrict__ x,
                                                const int* __restrict__ row_ptr,
                                                const int* __restrict__ csr_src,
                                                const float* __restrict__ bias,
                                                float* __restrict__ out, int n) {
    int lane = threadIdx.x & 63;
    int node = blockIdx.x * 4 + (threadIdx.x >> 6);
    if (node >= n) return;
    int p0 = row_ptr[node], p1 = row_ptr[node + 1];
    float cd = rsqrtf(fmaxf((float)(p1 - p0), 1.0f));
    if (D == 128) {
        float ax = 0.0f, ay = 0.0f;
        for (int p = p0; p < p1; ++p) {
            int s = csr_src[p];
            float2 v = ((const float2*)(x + ((size_t)s << 7)))[lane];
            ax += v.x; ay += v.y;
        }
        float2 b2 = ((const float2*)bias)[lane];
        float2 r;
        r.x = fmaxf(fmaf(ax, cd, b2.x), 0.0f);
        r.y = fmaxf(fmaf(ay, cd, b2.y), 0.0f);
        ((float2*)(out + ((size_t)node << 7)))[lane] = r;
    } else {
        float acc = 0.0f;
        for (int p = p0; p < p1; ++p) {
            int s = csr_src[p];
            acc += x[((size_t)s << 6) + lane];
        }
        out[((size_t)node << 6) + lane] = fmaxf(fmaf(acc, cd, bias[lane]), 0.0f);
    }
}

// ---------------- per-graph mean pooling (sum + count) ----------------
__global__ void pool_kernel(const float* __restrict__ x, const int* __restrict__ gid,
                            float* __restrict__ sums, float* __restrict__ cnts, int n) {
    __shared__ float ls[NGRAPH * 64];
    __shared__ float lc[NGRAPH];
    for (int i = threadIdx.x; i < NGRAPH * 64; i += blockDim.x) ls[i] = 0.0f;
    if (threadIdx.x < NGRAPH) lc[threadIdx.x] = 0.0f;
    __syncthreads();
    int total = n * 64;
    for (int i = blockIdx.x * blockDim.x + threadIdx.x; i < total;
         i += gridDim.x * blockDim.x) {
        int node = i >> 6, f = i & 63;
        int g = gid[node];
        atomicAdd(&ls[g * 64 + f], x[i]);
        if (f == 0) atomicAdd(&lc[g], 1.0f);
    }
    __syncthreads();
    for (int i = threadIdx.x; i < NGRAPH * 64; i += blockDim.x) atomicAdd(&sums[i], ls[i]);
    if (threadIdx.x < NGRAPH) atomicAdd(&cnts[threadIdx.x], lc[threadIdx.x]);
}

// ---------------- attention head: A = tanh(x @ aW1 + ab1) @ aW2 + ab2 ----------------
__global__ __launch_bounds__(256) void attn_kernel(const float* __restrict__ x,
                                                   const float* __restrict__ aW1,
                                                   const float* __restrict__ ab1,
                                                   const float* __restrict__ aW2,
                                                   const float* __restrict__ ab2,
                                                   float* __restrict__ A, int n) {
    __shared__ float w1[64 * 64];
    __shared__ float b1s[64];
    __shared__ float w2[64];
    for (int i = threadIdx.x; i < 64 * 64; i += 256) w1[i] = aW1[i];
    if (threadIdx.x < 64) { b1s[threadIdx.x] = ab1[threadIdx.x]; w2[threadIdx.x] = aW2[threadIdx.x]; }
    __syncthreads();
    int lane = threadIdx.x & 63;
    int wave = threadIdx.x >> 6;
    float bias2 = ab2[0];
    int node = blockIdx.x * 4 + wave;
    if (node >= n) return;
    float xv = x[(size_t)node * 64 + lane];
    float acc = b1s[lane];
#pragma unroll
    for (int k = 0; k < 64; k++) {
        float xk = __shfl(xv, k, 64);
        acc += xk * w1[k * 64 + lane];
    }
    float y = tanhf(acc);
    float p = y * w2[lane];
#pragma unroll
    for (int off = 32; off > 0; off >>= 1) p += __shfl_xor(p, off, 64);
    if (lane == 0) A[node] = p + bias2;
}

// ---------------- graph head: out = relu(hg @ cW1 + cb1) @ cW2 + cb2 ----------------
__global__ __launch_bounds__(1024) void head_kernel(const float* __restrict__ sums,
                                                    const float* __restrict__ cnts,
                                                    const float* __restrict__ cW1,
                                                    const float* __restrict__ cb1,
                                                    const float* __restrict__ cW2,
                                                    const float* __restrict__ cb2,
                                                    float* __restrict__ out) {
    __shared__ float hg[NGRAPH][64];
    __shared__ float z[NGRAPH][64];
    int tid = threadIdx.x;
    int g = tid >> 6, j = tid & 63;
    hg[g][j] = sums[tid] / fmaxf(cnts[g], 1.0f);
    __syncthreads();
    float acc = cb1[j];
#pragma unroll 4
    for (int k = 0; k < 64; k++) acc += hg[g][k] * cW1[k * 64 + j];
    z[g][j] = fmaxf(acc, 0.0f);
    __syncthreads();
    if (tid < NGRAPH * 2) {
        int gg = tid >> 1, c = tid & 1;
        float a2 = cb2[c];
#pragma unroll
        for (int jj = 0; jj < 64; jj++) a2 += z[gg][jj] * cW2[jj * 2 + c];
        out[gg * 2 + c] = a2;
    }
}

extern "C" void kernel_launch(void* const* d_in, const int* in_sizes, int n_in,
                              void* d_out, int out_size, void* d_ws, size_t ws_size,
                              hipStream_t stream) {
    const float* h   = (const float*)d_in[0];
    const int*   src = (const int*)d_in[1];
    const int*   dst = (const int*)d_in[2];
    const int*   gid = (const int*)d_in[3];
    const float* W1  = (const float*)d_in[4];
    const float* b1  = (const float*)d_in[5];
    const float* W2  = (const float*)d_in[6];
    const float* b2  = (const float*)d_in[7];
    const float* W3  = (const float*)d_in[8];
    const float* b3  = (const float*)d_in[9];
    const float* aW1 = (const float*)d_in[10];
    const float* ab1 = (const float*)d_in[11];
    const float* aW2 = (const float*)d_in[12];
    const float* ab2 = (const float*)d_in[13];
    const float* cW1 = (const float*)d_in[14];
    const float* cb1 = (const float*)d_in[15];
    const float* cW2 = (const float*)d_in[16];
    const float* cb2 = (const float*)d_in[17];

    float* out = (float*)d_out;   // 16*2 = 32 floats
    float* A   = out + 32;        // N floats

    const int N = N_NODES, E = N_EDGES;
    const int NB = (N + STILE - 1) / STILE;  // 25 scan tiles

    // ---- workspace layout
    float* ws       = (float*)d_ws;
    float* c_src    = ws;                          // N floats
    int*   row_ptr  = (int*)(ws + N);              // N+1 ints
    int*   cur      = row_ptr + (N + 1);           // N ints (din histogram -> fill cursor)
    int*   csr_src  = cur + N;                     // E ints
    int*   blk_sums = csr_src + E;                 // 64 ints
    int*   blk_off  = blk_sums + 64;               // 64 ints
    size_t off      = (size_t)N + (N + 1) + N + E + 128;
    off = (off + 15) & ~(size_t)15;
    float* bufA     = ws + off;                    // N*128 floats
    float* bufB     = bufA + (size_t)N * 128;      // N*128 floats
    int*   dout     = (int*)bufB;                  // N ints (aliased: consumed before bufB written)
    float* sums     = bufB + (size_t)N * 128;      // 16*64
    float* cnts     = sums + NGRAPH * 64;          // 16

    // ---- CSR build (once, reused by all 3 layers)
    hipMemsetAsync(cur, 0, N * sizeof(int), stream);
    hipMemsetAsync(dout, 0, N * sizeof(int), stream);
    hist_kernel<<<(E + 255) / 256, 256, 0, stream>>>(src, dst, dout, cur, E);
    csrc_kernel<<<(N + 255) / 256, 256, 0, stream>>>(dout, c_src, N);
    scan_blocks<<<NB, 256, 0, stream>>>(cur, row_ptr, blk_sums, N);
    scan_tops<<<1, 64, 0, stream>>>(blk_sums, blk_off, row_ptr + N, NB);
    scan_apply<<<(N + 255) / 256, 256, 0, stream>>>(blk_off, row_ptr, cur, N);
    fill_kernel<<<(E + 255) / 256, 256, 0, stream>>>(src, dst, cur, csr_src, E);

    // ---- layer 1: bufA = (h @ W1) * c_src ; bufB = relu(agg * c_dst + b1)
    gemm_scale<256, 128, 8><<<(N + 63) / 64, 256, 0, stream>>>(h, W1, c_src, bufA, N);
    agg_relu<128><<<(N + 3) / 4, 256, 0, stream>>>(bufA, row_ptr, csr_src, b1, bufB, N);

    // ---- layer 2
    gemm_scale<128, 128, 8><<<(N + 63) / 64, 256, 0, stream>>>(bufB, W2, c_src, bufA, N);
    agg_relu<128><<<(N + 3) / 4, 256, 0, stream>>>(bufA, row_ptr, csr_src, b2, bufB, N);

    // ---- layer 3: t3 = bufA[0:N*64]; x3 = bufA[N*64:N*128]
    float* t3 = bufA;
    float* x3 = bufA + (size_t)N * 64;
    gemm_scale<128, 64, 4><<<(N + 63) / 64, 256, 0, stream>>>(bufB, W3, c_src, t3, N);
    agg_relu<64><<<(N + 3) / 4, 256, 0, stream>>>(t3, row_ptr, csr_src, b3, x3, N);

    // ---- pooling
    hipMemsetAsync(sums, 0, (NGRAPH * 64 + NGRAPH) * sizeof(float), stream);
    pool_kernel<<<512, 256, 0, stream>>>(x3, gid, sums, cnts, N);

    // ---- attention scores A [N]
    attn_kernel<<<(N + 3) / 4, 256, 0, stream>>>(x3, aW1, ab1, aW2, ab2, A, N);

    // ---- graph head out [16,2]
    head_kernel<<<1, 1024, 0, stream>>>(sums, cnts, cW1, cb1, cW2, cb2, out);
}